// Round 2
// baseline (1944.334 us; speedup 1.0000x reference)
//
#include <hip/hip_runtime.h>

#define NN 100000
#define NE 1600000
#define BINS_PAD 100352   // 98 * 1024 >= NN
#define STR 72            // per-wave LDS row stride (u16), 16B-aligned rows

typedef short s8v __attribute__((ext_vector_type(8)));
typedef float f32x4 __attribute__((ext_vector_type(4)));
typedef unsigned short u16;

__device__ __forceinline__ u16 f2bf(float f) {
    union { float f; unsigned u; } v; v.f = f;
    unsigned r = v.u + 0x7FFFu + ((v.u >> 16) & 1u);
    return (u16)(r >> 16);
}
__device__ __forceinline__ unsigned pk2(float a, float b) {
    return (unsigned)f2bf(a) | ((unsigned)f2bf(b) << 16);
}

// ---------------- weight fragment packing (bf16, B-operand layout) -------------
__global__ void pack_weights(const float* __restrict__ pW,
                             const float* __restrict__ eW1, const float* __restrict__ eW2,
                             const float* __restrict__ nW1, const float* __restrict__ nW2,
                             u16* __restrict__ wpack) {
    int b = blockIdx.x, L = threadIdx.x;
    const float* src; int s, t;
    if (b < 16) { src = pW; s = b >> 2; t = b & 3; }
    else {
        int bb = b - 16, l = bb / 56, r = bb % 56;
        if (r < 24)      {            src = eW1 + l*192*64; s = r>>2; t = r&3; }
        else if (r < 32) { r -= 24;   src = eW2 + l*64*64;  s = r>>2; t = r&3; }
        else if (r < 48) { r -= 32;   src = nW1 + l*128*64; s = r>>2; t = r&3; }
        else             { r -= 48;   src = nW2 + l*64*64;  s = r>>2; t = r&3; }
    }
    int kbase = s*32 + (L>>4)*8;
    int n = t*16 + (L&15);
    u16* dst = wpack + (size_t)b*512 + (size_t)L*8;
#pragma unroll
    for (int j = 0; j < 8; ++j) dst[j] = f2bf(src[(kbase+j)*64 + n]);
}

// ---------------- counting sort of edges by col --------------------------------
__global__ void k_hist(const int* __restrict__ ei, int* __restrict__ hist) {
    int e = blockIdx.x * 256 + threadIdx.x;
    atomicAdd(&hist[ei[(size_t)NE + e]], 1);
}

__global__ void k_scan1(const int* __restrict__ hist, int* __restrict__ cursor,
                        int* __restrict__ blockSums) {
    __shared__ int sS[256];
    int t = threadIdx.x, b = blockIdx.x;
    int base = b*1024 + t*4;
    int v0 = hist[base], v1 = hist[base+1], v2 = hist[base+2], v3 = hist[base+3];
    int s4 = v0 + v1 + v2 + v3;
    sS[t] = s4; __syncthreads();
    for (int off = 1; off < 256; off <<= 1) {
        int x = (t >= off) ? sS[t-off] : 0;
        __syncthreads();
        sS[t] += x;
        __syncthreads();
    }
    int excl = sS[t] - s4;
    cursor[base] = excl; cursor[base+1] = excl+v0;
    cursor[base+2] = excl+v0+v1; cursor[base+3] = excl+v0+v1+v2;
    if (t == 255) blockSums[b] = sS[255];
}

__global__ void k_scan2(int* __restrict__ blockSums) {
    __shared__ int sS[128];
    int t = threadIdx.x;
    int v = (t < 98) ? blockSums[t] : 0;
    sS[t] = v; __syncthreads();
    for (int off = 1; off < 128; off <<= 1) {
        int x = (t >= off) ? sS[t-off] : 0;
        __syncthreads();
        sS[t] += x;
        __syncthreads();
    }
    if (t < 98) blockSums[t] = sS[t] - v;   // exclusive
}

__global__ void k_scan3(int* __restrict__ cursor, const int* __restrict__ blockSums) {
    int i = blockIdx.x*1024 + threadIdx.x*4;
    int add = blockSums[blockIdx.x];
    cursor[i] += add; cursor[i+1] += add; cursor[i+2] += add; cursor[i+3] += add;
}

// fused (row,col) scatter: one 8B store per edge instead of two 4B scatters
__global__ void k_scatter(const int* __restrict__ ei, int* __restrict__ cursor,
                          int2* __restrict__ rcP, int* __restrict__ pos) {
    int e = blockIdx.x * 256 + threadIdx.x;
    int c = ei[(size_t)NE + e];
    int p = atomicAdd(&cursor[c], 1);
    rcP[p] = make_int2(ei[e], c);
    pos[e] = p;
}

// permute edge_attr into sorted order + convert to bf16 (vectorized: 8 floats/thread)
__global__ void k_permute_ea(const float* __restrict__ ea, const int* __restrict__ pos,
                             u16* __restrict__ eaP) {
    size_t t = (size_t)blockIdx.x * 256 + threadIdx.x;
    int e = (int)(t >> 3), q = (int)(t & 7);
    int p = pos[e];
    const float4* src = (const float4*)(ea + (size_t)e*64 + q*8);
    float4 v0 = src[0], v1 = src[1];
    uint4 o;
    o.x = pk2(v0.x, v0.y); o.y = pk2(v0.z, v0.w);
    o.z = pk2(v1.x, v1.y); o.w = pk2(v1.z, v1.w);
    *(uint4*)(eaP + (size_t)p*64 + q*8) = o;
}

// ---------------- node projection: h = x @ pW + pb -----------------------------
__global__ __launch_bounds__(256) void node_proj(const float* __restrict__ x,
                                                 const float* __restrict__ pb,
                                                 const u16* __restrict__ wpack,
                                                 float* __restrict__ h,
                                                 u16* __restrict__ h_bf) {
    __shared__ __align__(16) u16 sX[64*136];
    const int tid = threadIdx.x;
    const int n0 = blockIdx.x * 64;
    for (int i = tid; i < 64*32; i += 256) {
        int node = i >> 5, c = i & 31;
        float4 v = make_float4(0.f, 0.f, 0.f, 0.f);
        if (n0 + node < NN) v = *(const float4*)(x + (size_t)(n0+node)*128 + c*4);
        *(uint2*)&sX[node*136 + c*4] = make_uint2(pk2(v.x, v.y), pk2(v.z, v.w));
    }
    __syncthreads();
    const int w = tid >> 6, L = tid & 63;
    const int m = L & 15, kc = L >> 4;
    const int wb = w * 16;
    const f32x4 z = {0.f, 0.f, 0.f, 0.f};
    f32x4 acc[4] = {z, z, z, z};
#pragma unroll
    for (int s = 0; s < 4; ++s) {
        s8v a = *(const s8v*)&sX[(wb+m)*136 + s*32 + kc*8];
#pragma unroll
        for (int t = 0; t < 4; ++t) {
            s8v bf = *(const s8v*)(wpack + ((size_t)(s*4+t)*64 + L)*8);
            acc[t] = __builtin_amdgcn_mfma_f32_16x16x32_bf16(a, bf, acc[t], 0, 0, 0);
        }
    }
#pragma unroll
    for (int t = 0; t < 4; ++t) {
        int u = t*16 + m;
        float bias = pb[u];
#pragma unroll
        for (int r = 0; r < 4; ++r) {
            int node = n0 + wb + kc*4 + r;
            if (node < NN) {
                float v = acc[t][r] + bias;
                h[(size_t)node*64 + u] = v;
                h_bf[(size_t)node*64 + u] = f2bf(v);
            }
        }
    }
}

// ---------------- fused per-layer edge kernel (sorted edges) -------------------
// 4 independent waves x 32 edges; NO block barriers. Per-wave LDS tile [32][STR]
// is single-buffered (ea_new overwrites t1 after it is consumed; t2 overwrites
// ea_new after it is consumed). Aggregation is a per-wave in-register segmented
// reduction over the GEMM4 accumulators: predicated sums over the segment edge
// range + shfl_xor across the 4 kc lane-groups, then one atomic per lane
// (feature L) per segment. LDS = 18,432 B -> 8 blocks/CU (vs 4 before).
__global__ __launch_bounds__(256, 6) void edge_layer(const int2* __restrict__ rcP,
                                                     const u16* __restrict__ h_bf,
                                                     u16* __restrict__ ea_bf,
                                                     const u16* __restrict__ wp,
                                                     const float* __restrict__ eb1,
                                                     const float* __restrict__ eb2,
                                                     const float* __restrict__ nb1,
                                                     const float* __restrict__ nb2,
                                                     float* __restrict__ agg,
                                                     int save_ea) {
    __shared__ __align__(16) u16 sB[4*32*STR];   // 18,432 B
    const int tid = threadIdx.x;
    const int w = tid >> 6, L = tid & 63;
    const int m = L & 15, kc = L >> 4;
    const int wb = w * 32;
    const size_t e0 = (size_t)blockIdx.x * 128;
    u16* sW = sB + w * 32 * STR;

    // one coalesced 8B load covers this wave's 32 (row,col) pairs
    int2 rc0 = rcP[e0 + wb + (L & 31)];
    int lcol = rc0.y;
    int rowI[2], colI[2];
#pragma unroll
    for (int g = 0; g < 2; ++g) {
        rowI[g] = __shfl(rc0.x, g*16 + m);
        colI[g] = __shfl(rc0.y, g*16 + m);
    }

    float be1[4], be2[4], bn1[4];
#pragma unroll
    for (int t = 0; t < 4; ++t) {
        int u = t*16 + m;
        be1[t] = eb1[u]; be2[t] = eb2[u]; bn1[t] = nb1[u];
    }
    float bn2L = nb2[L];

    const f32x4 z = {0.f, 0.f, 0.f, 0.f};
    f32x4 acc[2][4];

    // ---- GEMM1: [h_row|h_col|ea][*,192] @ eW1 -> t1 (LDS cols 0-63) ----
#pragma unroll
    for (int g = 0; g < 2; ++g)
#pragma unroll
        for (int t = 0; t < 4; ++t) acc[g][t] = z;
#pragma unroll
    for (int s = 0; s < 6; ++s) {
        s8v a[2];
#pragma unroll
        for (int g = 0; g < 2; ++g) {
            if (s < 2)
                a[g] = *(const s8v*)(h_bf + (size_t)rowI[g]*64 + s*32 + kc*8);
            else if (s < 4)
                a[g] = *(const s8v*)(h_bf + (size_t)colI[g]*64 + (s-2)*32 + kc*8);
            else
                a[g] = *(const s8v*)(ea_bf + (e0 + wb + g*16 + m)*64 + (s-4)*32 + kc*8);
        }
#pragma unroll
        for (int t = 0; t < 4; ++t) {
            s8v bf = *(const s8v*)(wp + ((size_t)(s*4+t)*64 + L)*8);
            acc[0][t] = __builtin_amdgcn_mfma_f32_16x16x32_bf16(a[0], bf, acc[0][t], 0, 0, 0);
            acc[1][t] = __builtin_amdgcn_mfma_f32_16x16x32_bf16(a[1], bf, acc[1][t], 0, 0, 0);
        }
    }
#pragma unroll
    for (int g = 0; g < 2; ++g)
#pragma unroll
        for (int t = 0; t < 4; ++t) {
            int u = t*16 + m;
#pragma unroll
            for (int r = 0; r < 4; ++r) {
                float v = acc[g][t][r] + be1[t];
                v = v > 0.f ? v : 0.f;
                sW[(g*16 + kc*4 + r)*STR + u] = f2bf(v);
            }
        }

    // ---- GEMM2: t1 @ eW2 -> ea_new (overwrites t1 region after reads) ----
    const u16* wp2 = wp + 24*512;
#pragma unroll
    for (int g = 0; g < 2; ++g)
#pragma unroll
        for (int t = 0; t < 4; ++t) acc[g][t] = z;
#pragma unroll
    for (int s = 0; s < 2; ++s) {
        s8v a0 = *(const s8v*)&sW[(m)*STR + s*32 + kc*8];
        s8v a1 = *(const s8v*)&sW[(16 + m)*STR + s*32 + kc*8];
#pragma unroll
        for (int t = 0; t < 4; ++t) {
            s8v bf = *(const s8v*)(wp2 + ((size_t)(s*4+t)*64 + L)*8);
            acc[0][t] = __builtin_amdgcn_mfma_f32_16x16x32_bf16(a0, bf, acc[0][t], 0, 0, 0);
            acc[1][t] = __builtin_amdgcn_mfma_f32_16x16x32_bf16(a1, bf, acc[1][t], 0, 0, 0);
        }
    }
#pragma unroll
    for (int g = 0; g < 2; ++g)
#pragma unroll
        for (int t = 0; t < 4; ++t) {
            int u = t*16 + m;
#pragma unroll
            for (int r = 0; r < 4; ++r) {
                float v = acc[g][t][r] + be2[t];
                sW[(g*16 + kc*4 + r)*STR + u] = f2bf(v);
            }
        }

    // ---- GEMM3: [h_row|ea_new][*,128] @ nW1 -> t2; optionally persist ea_new ----
    const u16* wp3 = wp + 32*512;
#pragma unroll
    for (int g = 0; g < 2; ++g)
#pragma unroll
        for (int t = 0; t < 4; ++t) acc[g][t] = z;
#pragma unroll
    for (int s = 0; s < 4; ++s) {
        s8v a[2];
#pragma unroll
        for (int g = 0; g < 2; ++g) {
            if (s < 2) {
                a[g] = *(const s8v*)(h_bf + (size_t)rowI[g]*64 + s*32 + kc*8);
            } else {
                a[g] = *(const s8v*)&sW[(g*16 + m)*STR + (s-2)*32 + kc*8];
                if (save_ea)
                    *(s8v*)(ea_bf + (e0 + wb + g*16 + m)*64 + (s-2)*32 + kc*8) = a[g];
            }
        }
#pragma unroll
        for (int t = 0; t < 4; ++t) {
            s8v bf = *(const s8v*)(wp3 + ((size_t)(s*4+t)*64 + L)*8);
            acc[0][t] = __builtin_amdgcn_mfma_f32_16x16x32_bf16(a[0], bf, acc[0][t], 0, 0, 0);
            acc[1][t] = __builtin_amdgcn_mfma_f32_16x16x32_bf16(a[1], bf, acc[1][t], 0, 0, 0);
        }
    }
#pragma unroll
    for (int g = 0; g < 2; ++g)
#pragma unroll
        for (int t = 0; t < 4; ++t) {
            int u = t*16 + m;
#pragma unroll
            for (int r = 0; r < 4; ++r) {
                float v = acc[g][t][r] + bn1[t];
                v = v > 0.f ? v : 0.f;
                sW[(g*16 + kc*4 + r)*STR + u] = f2bf(v);
            }
        }

    // ---- GEMM4: t2 @ nW2 -> msg (stays in acc registers) ----
    const u16* wp4 = wp + 48*512;
#pragma unroll
    for (int g = 0; g < 2; ++g)
#pragma unroll
        for (int t = 0; t < 4; ++t) acc[g][t] = z;
#pragma unroll
    for (int s = 0; s < 2; ++s) {
        s8v a0 = *(const s8v*)&sW[(m)*STR + s*32 + kc*8];
        s8v a1 = *(const s8v*)&sW[(16 + m)*STR + s*32 + kc*8];
#pragma unroll
        for (int t = 0; t < 4; ++t) {
            s8v bf = *(const s8v*)(wp4 + ((size_t)(s*4+t)*64 + L)*8);
            acc[0][t] = __builtin_amdgcn_mfma_f32_16x16x32_bf16(a0, bf, acc[0][t], 0, 0, 0);
            acc[1][t] = __builtin_amdgcn_mfma_f32_16x16x32_bf16(a1, bf, acc[1][t], 0, 0, 0);
        }
    }

    // ---- per-wave in-register segmented reduction -----------------------------
    // acc[g][t][r]: edge le = g*16 + kc*4 + r, feature f = t*16 + m. Lane L's
    // target feature is L = kc*16 + m (pick t == kc after cross-kc reduce).
    unsigned long long smask;
    {
        int prev = __shfl(lcol, (L + 63) & 63);
        bool sstart = (L < 32) && ((L == 0) || (lcol != prev));
        smask = __ballot(sstart);
    }
    while (smask) {
        int beg = (int)__builtin_ctzll(smask);
        smask &= smask - 1;
        int end = smask ? (int)__builtin_ctzll(smask) : 32;
        int node = __shfl(lcol, beg);
        float r0 = 0.f, r1 = 0.f, r2 = 0.f, r3 = 0.f;
#pragma unroll
        for (int g = 0; g < 2; ++g)
#pragma unroll
            for (int r = 0; r < 4; ++r) {
                int le = g*16 + kc*4 + r;
                bool in = (le >= beg) && (le < end);
                r0 += in ? acc[g][0][r] : 0.f;
                r1 += in ? acc[g][1][r] : 0.f;
                r2 += in ? acc[g][2][r] : 0.f;
                r3 += in ? acc[g][3][r] : 0.f;
            }
        r0 += __shfl_xor(r0, 16); r0 += __shfl_xor(r0, 32);
        r1 += __shfl_xor(r1, 16); r1 += __shfl_xor(r1, 32);
        r2 += __shfl_xor(r2, 16); r2 += __shfl_xor(r2, 32);
        r3 += __shfl_xor(r3, 16); r3 += __shfl_xor(r3, 32);
        float rv = (kc == 0) ? r0 : (kc == 1) ? r1 : (kc == 2) ? r2 : r3;
        rv += (float)(end - beg) * bn2L;
        unsafeAtomicAdd(&agg[(size_t)node*64 + L], rv);
    }
}

// ---------------- h = relu(agg + h); refresh bf16 copy; re-zero agg ------------
__global__ void update_h(float* __restrict__ h, float* __restrict__ agg,
                         u16* __restrict__ h_bf, int zero_agg, int write_hbf) {
    int i = (blockIdx.x * 256 + threadIdx.x) * 4;
    float4 a = *(const float4*)(agg + i);
    float4 hv = *(const float4*)(h + i);
    float4 v;
    v.x = fmaxf(a.x + hv.x, 0.f);
    v.y = fmaxf(a.y + hv.y, 0.f);
    v.z = fmaxf(a.z + hv.z, 0.f);
    v.w = fmaxf(a.w + hv.w, 0.f);
    *(float4*)(h + i) = v;
    if (write_hbf) *(uint2*)(h_bf + i) = make_uint2(pk2(v.x, v.y), pk2(v.z, v.w));
    if (zero_agg) *(float4*)(agg + i) = make_float4(0.f, 0.f, 0.f, 0.f);
}

// ---------------- mean pool ----------------------------------------------------
__global__ void pool1(const float* __restrict__ h, float* __restrict__ pooled) {
    float acc = 0.f;
    const int stride = gridDim.x * 256;
    for (int i = blockIdx.x * 256 + threadIdx.x; i < NN*64; i += stride)
        acc += h[i];
    __shared__ float sp[256];
    sp[threadIdx.x] = acc;
    __syncthreads();
    if (threadIdx.x < 64) {
        float v = sp[threadIdx.x] + sp[threadIdx.x+64] + sp[threadIdx.x+128] + sp[threadIdx.x+192];
        unsafeAtomicAdd(&pooled[threadIdx.x], v);
    }
}

__global__ void pool2(const float* __restrict__ pooled, const float* __restrict__ lW,
                      const float* __restrict__ lb, float* __restrict__ out) {
    int k = threadIdx.x;   // 64 threads
    float v = pooled[k] * (1.0f / NN);
#pragma unroll
    for (int o = 0; o < 3; ++o) {
        float p = v * lW[k*3 + o];
        for (int off = 32; off > 0; off >>= 1)
            p += __shfl_down(p, off);
        if (k == 0) out[o] = p + lb[o];
    }
}

extern "C" void kernel_launch(void* const* d_in, const int* in_sizes, int n_in,
                              void* d_out, int out_size, void* d_ws, size_t ws_size,
                              hipStream_t stream) {
    const float* x         = (const float*)d_in[0];
    const int*   ei        = (const int*)d_in[1];
    const float* edge_attr = (const float*)d_in[2];
    const float* pW        = (const float*)d_in[3];
    const float* pb        = (const float*)d_in[4];
    const float* eW1       = (const float*)d_in[5];
    const float* eb1       = (const float*)d_in[6];
    const float* eW2       = (const float*)d_in[7];
    const float* eb2       = (const float*)d_in[8];
    const float* nW1       = (const float*)d_in[9];
    const float* nb1       = (const float*)d_in[10];
    const float* nW2       = (const float*)d_in[11];
    const float* nb2       = (const float*)d_in[12];
    const float* lW        = (const float*)d_in[13];
    const float* lb        = (const float*)d_in[14];
    float* out = (float*)d_out;

    char* ws = (char*)d_ws;
    float* h     = (float*)(ws);                         // 25,600,000 B
    float* agg   = (float*)(ws + 25600000);              // 25,600,000 B
    u16*   h_bf  = (u16*)  (ws + 51200000);              // 12,800,000 B
    u16*   eaP   = (u16*)  (ws + 64000000);              // 204,800,000 B (sorted-order ea)
    u16*   wpack = (u16*)  (ws + 268800000);             // 188,416 B
    float* pooled= (float*)(ws + 268988416);             // 256 B
    int2*  rcP   = (int2*) (ws + 268988672);             // 12,800,000 B (ends 281,788,672)
    // sort scratch overlaid on agg (dead until after preprocessing):
    int* hist      = (int*)agg;                          // BINS_PAD ints
    int* cursor    = hist + BINS_PAD;                    // BINS_PAD ints
    int* blockSums = cursor + BINS_PAD;                  // 128 ints
    int* pos       = blockSums + 128;                    // NE ints (~7.2 MB total < 25.6 MB)

    // ---- counting sort by col (once; reused by all 3 layers) ----
    hipMemsetAsync(hist, 0, BINS_PAD*4, stream);
    k_hist<<<NE/256, 256, 0, stream>>>(ei, hist);
    k_scan1<<<98, 256, 0, stream>>>(hist, cursor, blockSums);
    k_scan2<<<1, 128, 0, stream>>>(blockSums);
    k_scan3<<<98, 256, 0, stream>>>(cursor, blockSums);
    k_scatter<<<NE/256, 256, 0, stream>>>(ei, cursor, rcP, pos);
    k_permute_ea<<<NE*8/256, 256, 0, stream>>>(edge_attr, pos, eaP);

    pack_weights<<<184, 64, 0, stream>>>(pW, eW1, eW2, nW1, nW2, wpack);
    node_proj<<<(NN + 63)/64, 256, 0, stream>>>(x, pb, wpack, h, h_bf);

    hipMemsetAsync(agg, 0, (size_t)NN*64*4, stream);     // clobbers sort scratch (dead)
    for (int l = 0; l < 3; ++l) {
        edge_layer<<<NE/128, 256, 0, stream>>>(rcP, h_bf, eaP,
                                               wpack + (16 + l*56)*512,
                                               eb1 + l*64, eb2 + l*64, nb1 + l*64, nb2 + l*64,
                                               agg, l < 2 ? 1 : 0);
        update_h<<<NN*64/4/256, 256, 0, stream>>>(h, agg, h_bf, l < 2 ? 1 : 0, l < 2 ? 1 : 0);
    }
    hipMemsetAsync(pooled, 0, 64*4, stream);
    pool1<<<256, 256, 0, stream>>>(h, pooled);
    pool2<<<1, 64, 0, stream>>>(pooled, lW, lb, out);
}

// Round 3
// 1724.019 us; speedup vs baseline: 1.1278x; 1.1278x over previous
//
#include <hip/hip_runtime.h>

#define NN 100000
#define NE 1600000
#define BINS_PAD 100352   // 98 * 1024 >= NN
#define STR 72            // per-wave LDS row stride (u16), 16B-aligned rows

typedef short s8v __attribute__((ext_vector_type(8)));
typedef float f32x4 __attribute__((ext_vector_type(4)));
typedef unsigned short u16;

__device__ __forceinline__ u16 f2bf(float f) {
    union { float f; unsigned u; } v; v.f = f;
    unsigned r = v.u + 0x7FFFu + ((v.u >> 16) & 1u);
    return (u16)(r >> 16);
}
__device__ __forceinline__ unsigned pk2(float a, float b) {
    return (unsigned)f2bf(a) | ((unsigned)f2bf(b) << 16);
}

// ---------------- weight fragment packing (bf16, B-operand layout) -------------
__global__ void pack_weights(const float* __restrict__ pW,
                             const float* __restrict__ eW1, const float* __restrict__ eW2,
                             const float* __restrict__ nW1, const float* __restrict__ nW2,
                             u16* __restrict__ wpack) {
    int b = blockIdx.x, L = threadIdx.x;
    const float* src; int s, t;
    if (b < 16) { src = pW; s = b >> 2; t = b & 3; }
    else {
        int bb = b - 16, l = bb / 56, r = bb % 56;
        if (r < 24)      {            src = eW1 + l*192*64; s = r>>2; t = r&3; }
        else if (r < 32) { r -= 24;   src = eW2 + l*64*64;  s = r>>2; t = r&3; }
        else if (r < 48) { r -= 32;   src = nW1 + l*128*64; s = r>>2; t = r&3; }
        else             { r -= 48;   src = nW2 + l*64*64;  s = r>>2; t = r&3; }
    }
    int kbase = s*32 + (L>>4)*8;
    int n = t*16 + (L&15);
    u16* dst = wpack + (size_t)b*512 + (size_t)L*8;
#pragma unroll
    for (int j = 0; j < 8; ++j) dst[j] = f2bf(src[(kbase+j)*64 + n]);
}

// ---------------- counting sort of edges by col --------------------------------
__global__ void k_hist(const int* __restrict__ ei, int* __restrict__ hist) {
    int e = blockIdx.x * 256 + threadIdx.x;
    atomicAdd(&hist[ei[(size_t)NE + e]], 1);
}

__global__ void k_scan1(const int* __restrict__ hist, int* __restrict__ cursor,
                        int* __restrict__ blockSums) {
    __shared__ int sS[256];
    int t = threadIdx.x, b = blockIdx.x;
    int base = b*1024 + t*4;
    int v0 = hist[base], v1 = hist[base+1], v2 = hist[base+2], v3 = hist[base+3];
    int s4 = v0 + v1 + v2 + v3;
    sS[t] = s4; __syncthreads();
    for (int off = 1; off < 256; off <<= 1) {
        int x = (t >= off) ? sS[t-off] : 0;
        __syncthreads();
        sS[t] += x;
        __syncthreads();
    }
    int excl = sS[t] - s4;
    cursor[base] = excl; cursor[base+1] = excl+v0;
    cursor[base+2] = excl+v0+v1; cursor[base+3] = excl+v0+v1+v2;
    if (t == 255) blockSums[b] = sS[255];
}

__global__ void k_scan2(int* __restrict__ blockSums) {
    __shared__ int sS[128];
    int t = threadIdx.x;
    int v = (t < 98) ? blockSums[t] : 0;
    sS[t] = v; __syncthreads();
    for (int off = 1; off < 128; off <<= 1) {
        int x = (t >= off) ? sS[t-off] : 0;
        __syncthreads();
        sS[t] += x;
        __syncthreads();
    }
    if (t < 98) blockSums[t] = sS[t] - v;   // exclusive
}

__global__ void k_scan3(int* __restrict__ cursor, const int* __restrict__ blockSums) {
    int i = blockIdx.x*1024 + threadIdx.x*4;
    int add = blockSums[blockIdx.x];
    cursor[i] += add; cursor[i+1] += add; cursor[i+2] += add; cursor[i+3] += add;
}

// fused (row,col) scatter: one 8B store per edge instead of two 4B scatters
__global__ void k_scatter(const int* __restrict__ ei, int* __restrict__ cursor,
                          int2* __restrict__ rcP, int* __restrict__ pos) {
    int e = blockIdx.x * 256 + threadIdx.x;
    int c = ei[(size_t)NE + e];
    int p = atomicAdd(&cursor[c], 1);
    rcP[p] = make_int2(ei[e], c);
    pos[e] = p;
}

// permute edge_attr into sorted order + convert to bf16 (vectorized: 8 floats/thread)
__global__ void k_permute_ea(const float* __restrict__ ea, const int* __restrict__ pos,
                             u16* __restrict__ eaP) {
    size_t t = (size_t)blockIdx.x * 256 + threadIdx.x;
    int e = (int)(t >> 3), q = (int)(t & 7);
    int p = pos[e];
    const float4* src = (const float4*)(ea + (size_t)e*64 + q*8);
    float4 v0 = src[0], v1 = src[1];
    uint4 o;
    o.x = pk2(v0.x, v0.y); o.y = pk2(v0.z, v0.w);
    o.z = pk2(v1.x, v1.y); o.w = pk2(v1.z, v1.w);
    *(uint4*)(eaP + (size_t)p*64 + q*8) = o;
}

// ---------------- node projection: h = x @ pW + pb -----------------------------
__global__ __launch_bounds__(256) void node_proj(const float* __restrict__ x,
                                                 const float* __restrict__ pb,
                                                 const u16* __restrict__ wpack,
                                                 float* __restrict__ h,
                                                 u16* __restrict__ h_bf) {
    __shared__ __align__(16) u16 sX[64*136];
    const int tid = threadIdx.x;
    const int n0 = blockIdx.x * 64;
    for (int i = tid; i < 64*32; i += 256) {
        int node = i >> 5, c = i & 31;
        float4 v = make_float4(0.f, 0.f, 0.f, 0.f);
        if (n0 + node < NN) v = *(const float4*)(x + (size_t)(n0+node)*128 + c*4);
        *(uint2*)&sX[node*136 + c*4] = make_uint2(pk2(v.x, v.y), pk2(v.z, v.w));
    }
    __syncthreads();
    const int w = tid >> 6, L = tid & 63;
    const int m = L & 15, kc = L >> 4;
    const int wb = w * 16;
    const f32x4 z = {0.f, 0.f, 0.f, 0.f};
    f32x4 acc[4] = {z, z, z, z};
#pragma unroll
    for (int s = 0; s < 4; ++s) {
        s8v a = *(const s8v*)&sX[(wb+m)*136 + s*32 + kc*8];
#pragma unroll
        for (int t = 0; t < 4; ++t) {
            s8v bf = *(const s8v*)(wpack + ((size_t)(s*4+t)*64 + L)*8);
            acc[t] = __builtin_amdgcn_mfma_f32_16x16x32_bf16(a, bf, acc[t], 0, 0, 0);
        }
    }
#pragma unroll
    for (int t = 0; t < 4; ++t) {
        int u = t*16 + m;
        float bias = pb[u];
#pragma unroll
        for (int r = 0; r < 4; ++r) {
            int node = n0 + wb + kc*4 + r;
            if (node < NN) {
                float v = acc[t][r] + bias;
                h[(size_t)node*64 + u] = v;
                h_bf[(size_t)node*64 + u] = f2bf(v);
            }
        }
    }
}

// ---------------- fused per-layer edge kernel (sorted edges) -------------------
// 4 independent waves x 32 edges; NO block barriers. Per-wave LDS tile [32][STR]
// single-buffered. Aggregation: per-wave in-register segmented reduction.
// __launch_bounds__(256,4): 128-reg budget -- ~88 regs live (32 acc + addr/misc)
// MUST NOT spill (Round-1's (256,6)=80-reg budget spilled the acc array ->
// +600 MB scratch traffic, 371 us/layer).
__global__ __launch_bounds__(256, 4) void edge_layer(const int2* __restrict__ rcP,
                                                     const u16* __restrict__ h_bf,
                                                     u16* __restrict__ ea_bf,
                                                     const u16* __restrict__ wp,
                                                     const float* __restrict__ eb1,
                                                     const float* __restrict__ eb2,
                                                     const float* __restrict__ nb1,
                                                     const float* __restrict__ nb2,
                                                     float* __restrict__ agg,
                                                     int save_ea) {
    __shared__ __align__(16) u16 sB[4*32*STR];   // 18,432 B
    const int tid = threadIdx.x;
    const int w = tid >> 6, L = tid & 63;
    const int m = L & 15, kc = L >> 4;
    const int wb = w * 32;
    const size_t e0 = (size_t)blockIdx.x * 128;
    u16* sW = sB + w * 32 * STR;

    // one coalesced 8B load covers this wave's 32 (row,col) pairs
    int2 rc0 = rcP[e0 + wb + (L & 31)];
    int lcol = rc0.y;
    int rowI[2], colI[2];
#pragma unroll
    for (int g = 0; g < 2; ++g) {
        rowI[g] = __shfl(rc0.x, g*16 + m);
        colI[g] = __shfl(rc0.y, g*16 + m);
    }

    const f32x4 z = {0.f, 0.f, 0.f, 0.f};
    f32x4 acc[2][4];

    // ---- GEMM1: [h_row|h_col|ea][*,192] @ eW1 -> t1 (LDS) ----
#pragma unroll
    for (int g = 0; g < 2; ++g)
#pragma unroll
        for (int t = 0; t < 4; ++t) acc[g][t] = z;
#pragma unroll
    for (int s = 0; s < 6; ++s) {
        s8v a[2];
#pragma unroll
        for (int g = 0; g < 2; ++g) {
            if (s < 2)
                a[g] = *(const s8v*)(h_bf + (size_t)rowI[g]*64 + s*32 + kc*8);
            else if (s < 4)
                a[g] = *(const s8v*)(h_bf + (size_t)colI[g]*64 + (s-2)*32 + kc*8);
            else
                a[g] = *(const s8v*)(ea_bf + (e0 + wb + g*16 + m)*64 + (s-4)*32 + kc*8);
        }
#pragma unroll
        for (int t = 0; t < 4; ++t) {
            s8v bf = *(const s8v*)(wp + ((size_t)(s*4+t)*64 + L)*8);
            acc[0][t] = __builtin_amdgcn_mfma_f32_16x16x32_bf16(a[0], bf, acc[0][t], 0, 0, 0);
            acc[1][t] = __builtin_amdgcn_mfma_f32_16x16x32_bf16(a[1], bf, acc[1][t], 0, 0, 0);
        }
    }
    // bias loaded at use site (not held across GEMMs -> lower reg pressure)
#pragma unroll
    for (int g = 0; g < 2; ++g)
#pragma unroll
        for (int t = 0; t < 4; ++t) {
            int u = t*16 + m;
            float be = eb1[u];
#pragma unroll
            for (int r = 0; r < 4; ++r) {
                float v = acc[g][t][r] + be;
                v = v > 0.f ? v : 0.f;
                sW[(g*16 + kc*4 + r)*STR + u] = f2bf(v);
            }
        }

    // ---- GEMM2: t1 @ eW2 -> ea_new (overwrites t1 region after reads) ----
    const u16* wp2 = wp + 24*512;
#pragma unroll
    for (int g = 0; g < 2; ++g)
#pragma unroll
        for (int t = 0; t < 4; ++t) acc[g][t] = z;
#pragma unroll
    for (int s = 0; s < 2; ++s) {
        s8v a0 = *(const s8v*)&sW[(m)*STR + s*32 + kc*8];
        s8v a1 = *(const s8v*)&sW[(16 + m)*STR + s*32 + kc*8];
#pragma unroll
        for (int t = 0; t < 4; ++t) {
            s8v bf = *(const s8v*)(wp2 + ((size_t)(s*4+t)*64 + L)*8);
            acc[0][t] = __builtin_amdgcn_mfma_f32_16x16x32_bf16(a0, bf, acc[0][t], 0, 0, 0);
            acc[1][t] = __builtin_amdgcn_mfma_f32_16x16x32_bf16(a1, bf, acc[1][t], 0, 0, 0);
        }
    }
#pragma unroll
    for (int g = 0; g < 2; ++g)
#pragma unroll
        for (int t = 0; t < 4; ++t) {
            int u = t*16 + m;
            float be = eb2[u];
#pragma unroll
            for (int r = 0; r < 4; ++r) {
                float v = acc[g][t][r] + be;
                sW[(g*16 + kc*4 + r)*STR + u] = f2bf(v);
            }
        }

    // ---- GEMM3: [h_row|ea_new][*,128] @ nW1 -> t2; optionally persist ea_new ----
    const u16* wp3 = wp + 32*512;
#pragma unroll
    for (int g = 0; g < 2; ++g)
#pragma unroll
        for (int t = 0; t < 4; ++t) acc[g][t] = z;
#pragma unroll
    for (int s = 0; s < 4; ++s) {
        s8v a[2];
#pragma unroll
        for (int g = 0; g < 2; ++g) {
            if (s < 2) {
                a[g] = *(const s8v*)(h_bf + (size_t)rowI[g]*64 + s*32 + kc*8);
            } else {
                a[g] = *(const s8v*)&sW[(g*16 + m)*STR + (s-2)*32 + kc*8];
                if (save_ea)
                    *(s8v*)(ea_bf + (e0 + wb + g*16 + m)*64 + (s-2)*32 + kc*8) = a[g];
            }
        }
#pragma unroll
        for (int t = 0; t < 4; ++t) {
            s8v bf = *(const s8v*)(wp3 + ((size_t)(s*4+t)*64 + L)*8);
            acc[0][t] = __builtin_amdgcn_mfma_f32_16x16x32_bf16(a[0], bf, acc[0][t], 0, 0, 0);
            acc[1][t] = __builtin_amdgcn_mfma_f32_16x16x32_bf16(a[1], bf, acc[1][t], 0, 0, 0);
        }
    }
#pragma unroll
    for (int g = 0; g < 2; ++g)
#pragma unroll
        for (int t = 0; t < 4; ++t) {
            int u = t*16 + m;
            float be = nb1[u];
#pragma unroll
            for (int r = 0; r < 4; ++r) {
                float v = acc[g][t][r] + be;
                v = v > 0.f ? v : 0.f;
                sW[(g*16 + kc*4 + r)*STR + u] = f2bf(v);
            }
        }

    // ---- GEMM4: t2 @ nW2 -> msg (stays in acc registers) ----
    const u16* wp4 = wp + 48*512;
#pragma unroll
    for (int g = 0; g < 2; ++g)
#pragma unroll
        for (int t = 0; t < 4; ++t) acc[g][t] = z;
#pragma unroll
    for (int s = 0; s < 2; ++s) {
        s8v a0 = *(const s8v*)&sW[(m)*STR + s*32 + kc*8];
        s8v a1 = *(const s8v*)&sW[(16 + m)*STR + s*32 + kc*8];
#pragma unroll
        for (int t = 0; t < 4; ++t) {
            s8v bf = *(const s8v*)(wp4 + ((size_t)(s*4+t)*64 + L)*8);
            acc[0][t] = __builtin_amdgcn_mfma_f32_16x16x32_bf16(a0, bf, acc[0][t], 0, 0, 0);
            acc[1][t] = __builtin_amdgcn_mfma_f32_16x16x32_bf16(a1, bf, acc[1][t], 0, 0, 0);
        }
    }

    // ---- per-wave in-register segmented reduction -----------------------------
    // acc[g][t][r]: edge le = g*16 + kc*4 + r, feature f = t*16 + m. Lane L's
    // target feature is L = kc*16 + m (select t == kc after cross-kc reduce).
    float bn2L = nb2[L];
    unsigned long long smask;
    {
        int prev = __shfl(lcol, (L + 63) & 63);
        bool sstart = (L < 32) && ((L == 0) || (lcol != prev));
        smask = __ballot(sstart);
    }
    while (smask) {
        int beg = (int)__builtin_ctzll(smask);
        smask &= smask - 1;
        int end = smask ? (int)__builtin_ctzll(smask) : 32;
        int node = __shfl(lcol, beg);
        float rv = 0.f;
        // sequential over t: only one partial live at a time (reg pressure)
#pragma unroll
        for (int t = 0; t < 4; ++t) {
            float rt = 0.f;
#pragma unroll
            for (int g = 0; g < 2; ++g)
#pragma unroll
                for (int r = 0; r < 4; ++r) {
                    int le = g*16 + kc*4 + r;
                    bool in = (le >= beg) && (le < end);
                    rt += in ? acc[g][t][r] : 0.f;
                }
            rt += __shfl_xor(rt, 16);
            rt += __shfl_xor(rt, 32);
            rv = (kc == t) ? rt : rv;
        }
        rv += (float)(end - beg) * bn2L;
        unsafeAtomicAdd(&agg[(size_t)node*64 + L], rv);
    }
}

// ---------------- h = relu(agg + h); refresh bf16 copy; re-zero agg ------------
__global__ void update_h(float* __restrict__ h, float* __restrict__ agg,
                         u16* __restrict__ h_bf, int zero_agg, int write_hbf) {
    int i = (blockIdx.x * 256 + threadIdx.x) * 4;
    float4 a = *(const float4*)(agg + i);
    float4 hv = *(const float4*)(h + i);
    float4 v;
    v.x = fmaxf(a.x + hv.x, 0.f);
    v.y = fmaxf(a.y + hv.y, 0.f);
    v.z = fmaxf(a.z + hv.z, 0.f);
    v.w = fmaxf(a.w + hv.w, 0.f);
    *(float4*)(h + i) = v;
    if (write_hbf) *(uint2*)(h_bf + i) = make_uint2(pk2(v.x, v.y), pk2(v.z, v.w));
    if (zero_agg) *(float4*)(agg + i) = make_float4(0.f, 0.f, 0.f, 0.f);
}

// ---------------- mean pool ----------------------------------------------------
__global__ void pool1(const float* __restrict__ h, float* __restrict__ pooled) {
    float acc = 0.f;
    const int stride = gridDim.x * 256;
    for (int i = blockIdx.x * 256 + threadIdx.x; i < NN*64; i += stride)
        acc += h[i];
    __shared__ float sp[256];
    sp[threadIdx.x] = acc;
    __syncthreads();
    if (threadIdx.x < 64) {
        float v = sp[threadIdx.x] + sp[threadIdx.x+64] + sp[threadIdx.x+128] + sp[threadIdx.x+192];
        unsafeAtomicAdd(&pooled[threadIdx.x], v);
    }
}

__global__ void pool2(const float* __restrict__ pooled, const float* __restrict__ lW,
                      const float* __restrict__ lb, float* __restrict__ out) {
    int k = threadIdx.x;   // 64 threads
    float v = pooled[k] * (1.0f / NN);
#pragma unroll
    for (int o = 0; o < 3; ++o) {
        float p = v * lW[k*3 + o];
        for (int off = 32; off > 0; off >>= 1)
            p += __shfl_down(p, off);
        if (k == 0) out[o] = p + lb[o];
    }
}

extern "C" void kernel_launch(void* const* d_in, const int* in_sizes, int n_in,
                              void* d_out, int out_size, void* d_ws, size_t ws_size,
                              hipStream_t stream) {
    const float* x         = (const float*)d_in[0];
    const int*   ei        = (const int*)d_in[1];
    const float* edge_attr = (const float*)d_in[2];
    const float* pW        = (const float*)d_in[3];
    const float* pb        = (const float*)d_in[4];
    const float* eW1       = (const float*)d_in[5];
    const float* eb1       = (const float*)d_in[6];
    const float* eW2       = (const float*)d_in[7];
    const float* eb2       = (const float*)d_in[8];
    const float* nW1       = (const float*)d_in[9];
    const float* nb1       = (const float*)d_in[10];
    const float* nW2       = (const float*)d_in[11];
    const float* nb2       = (const float*)d_in[12];
    const float* lW        = (const float*)d_in[13];
    const float* lb        = (const float*)d_in[14];
    float* out = (float*)d_out;

    char* ws = (char*)d_ws;
    float* h     = (float*)(ws);                         // 25,600,000 B
    float* agg   = (float*)(ws + 25600000);              // 25,600,000 B
    u16*   h_bf  = (u16*)  (ws + 51200000);              // 12,800,000 B
    u16*   eaP   = (u16*)  (ws + 64000000);              // 204,800,000 B (sorted-order ea)
    u16*   wpack = (u16*)  (ws + 268800000);             // 188,416 B
    float* pooled= (float*)(ws + 268988416);             // 256 B
    int2*  rcP   = (int2*) (ws + 268988672);             // 12,800,000 B (ends 281,788,672)
    // sort scratch overlaid on agg (dead until after preprocessing):
    int* hist      = (int*)agg;                          // BINS_PAD ints
    int* cursor    = hist + BINS_PAD;                    // BINS_PAD ints
    int* blockSums = cursor + BINS_PAD;                  // 128 ints
    int* pos       = blockSums + 128;                    // NE ints (~7.2 MB total < 25.6 MB)

    // ---- counting sort by col (once; reused by all 3 layers) ----
    hipMemsetAsync(hist, 0, BINS_PAD*4, stream);
    k_hist<<<NE/256, 256, 0, stream>>>(ei, hist);
    k_scan1<<<98, 256, 0, stream>>>(hist, cursor, blockSums);
    k_scan2<<<1, 128, 0, stream>>>(blockSums);
    k_scan3<<<98, 256, 0, stream>>>(cursor, blockSums);
    k_scatter<<<NE/256, 256, 0, stream>>>(ei, cursor, rcP, pos);
    k_permute_ea<<<NE*8/256, 256, 0, stream>>>(edge_attr, pos, eaP);

    pack_weights<<<184, 64, 0, stream>>>(pW, eW1, eW2, nW1, nW2, wpack);
    node_proj<<<(NN + 63)/64, 256, 0, stream>>>(x, pb, wpack, h, h_bf);

    hipMemsetAsync(agg, 0, (size_t)NN*64*4, stream);     // clobbers sort scratch (dead)
    for (int l = 0; l < 3; ++l) {
        edge_layer<<<NE/128, 256, 0, stream>>>(rcP, h_bf, eaP,
                                               wpack + (16 + l*56)*512,
                                               eb1 + l*64, eb2 + l*64, nb1 + l*64, nb2 + l*64,
                                               agg, l < 2 ? 1 : 0);
        update_h<<<NN*64/4/256, 256, 0, stream>>>(h, agg, h_bf, l < 2 ? 1 : 0, l < 2 ? 1 : 0);
    }
    hipMemsetAsync(pooled, 0, 64*4, stream);
    pool1<<<256, 256, 0, stream>>>(h, pooled);
    pool2<<<1, 64, 0, stream>>>(pooled, lW, lb, out);
}

// Round 6
// 1604.986 us; speedup vs baseline: 1.2114x; 1.0742x over previous
//
#include <hip/hip_runtime.h>

#define NN 100000
#define NE 1600000
#define BINS_PAD 100352   // 98 * 1024 >= NN
#define STR 72            // per-wave LDS row stride (u16), 16B-aligned rows

typedef short s8v __attribute__((ext_vector_type(8)));
typedef float f32x4 __attribute__((ext_vector_type(4)));
typedef unsigned short u16;

__device__ __forceinline__ u16 f2bf(float f) {
    union { float f; unsigned u; } v; v.f = f;
    unsigned r = v.u + 0x7FFFu + ((v.u >> 16) & 1u);
    return (u16)(r >> 16);
}
__device__ __forceinline__ unsigned pk2(float a, float b) {
    return (unsigned)f2bf(a) | ((unsigned)f2bf(b) << 16);
}

// ---------------- weight fragment packing (bf16, B-operand layout) -------------
__global__ void pack_weights(const float* __restrict__ pW,
                             const float* __restrict__ eW1, const float* __restrict__ eW2,
                             const float* __restrict__ nW1, const float* __restrict__ nW2,
                             u16* __restrict__ wpack) {
    int b = blockIdx.x, L = threadIdx.x;
    const float* src; int s, t;
    if (b < 16) { src = pW; s = b >> 2; t = b & 3; }
    else {
        int bb = b - 16, l = bb / 56, r = bb % 56;
        if (r < 24)      {            src = eW1 + l*192*64; s = r>>2; t = r&3; }
        else if (r < 32) { r -= 24;   src = eW2 + l*64*64;  s = r>>2; t = r&3; }
        else if (r < 48) { r -= 32;   src = nW1 + l*128*64; s = r>>2; t = r&3; }
        else             { r -= 48;   src = nW2 + l*64*64;  s = r>>2; t = r&3; }
    }
    int kbase = s*32 + (L>>4)*8;
    int n = t*16 + (L&15);
    u16* dst = wpack + (size_t)b*512 + (size_t)L*8;
#pragma unroll
    for (int j = 0; j < 8; ++j) dst[j] = f2bf(src[(kbase+j)*64 + n]);
}

// ---------------- counting sort of edges by col --------------------------------
__global__ void k_hist(const int* __restrict__ ei, int* __restrict__ hist) {
    int e = blockIdx.x * 256 + threadIdx.x;
    atomicAdd(&hist[ei[(size_t)NE + e]], 1);
}

__global__ void k_scan1(const int* __restrict__ hist, int* __restrict__ cursor,
                        int* __restrict__ blockSums) {
    __shared__ int sS[256];
    int t = threadIdx.x, b = blockIdx.x;
    int base = b*1024 + t*4;
    int v0 = hist[base], v1 = hist[base+1], v2 = hist[base+2], v3 = hist[base+3];
    int s4 = v0 + v1 + v2 + v3;
    sS[t] = s4; __syncthreads();
    for (int off = 1; off < 256; off <<= 1) {
        int x = (t >= off) ? sS[t-off] : 0;
        __syncthreads();
        sS[t] += x;
        __syncthreads();
    }
    int excl = sS[t] - s4;
    cursor[base] = excl; cursor[base+1] = excl+v0;
    cursor[base+2] = excl+v0+v1; cursor[base+3] = excl+v0+v1+v2;
    if (t == 255) blockSums[b] = sS[255];
}

__global__ void k_scan2(int* __restrict__ blockSums) {
    __shared__ int sS[128];
    int t = threadIdx.x;
    int v = (t < 98) ? blockSums[t] : 0;
    sS[t] = v; __syncthreads();
    for (int off = 1; off < 128; off <<= 1) {
        int x = (t >= off) ? sS[t-off] : 0;
        __syncthreads();
        sS[t] += x;
        __syncthreads();
    }
    if (t < 98) blockSums[t] = sS[t] - v;   // exclusive
}

__global__ void k_scan3(int* __restrict__ cursor, const int* __restrict__ blockSums) {
    int i = blockIdx.x*1024 + threadIdx.x*4;
    int add = blockSums[blockIdx.x];
    cursor[i] += add; cursor[i+1] += add; cursor[i+2] += add; cursor[i+3] += add;
}

// fused (row,col) scatter: one 8B store per edge instead of two 4B scatters
__global__ void k_scatter(const int* __restrict__ ei, int* __restrict__ cursor,
                          int2* __restrict__ rcP, int* __restrict__ pos) {
    int e = blockIdx.x * 256 + threadIdx.x;
    int c = ei[(size_t)NE + e];
    int p = atomicAdd(&cursor[c], 1);
    rcP[p] = make_int2(ei[e], c);
    pos[e] = p;
}

// permute edge_attr into sorted order + convert to bf16 (vectorized: 8 floats/thread)
__global__ void k_permute_ea(const float* __restrict__ ea, const int* __restrict__ pos,
                             u16* __restrict__ eaP) {
    size_t t = (size_t)blockIdx.x * 256 + threadIdx.x;
    int e = (int)(t >> 3), q = (int)(t & 7);
    int p = pos[e];
    const float4* src = (const float4*)(ea + (size_t)e*64 + q*8);
    float4 v0 = src[0], v1 = src[1];
    uint4 o;
    o.x = pk2(v0.x, v0.y); o.y = pk2(v0.z, v0.w);
    o.z = pk2(v1.x, v1.y); o.w = pk2(v1.z, v1.w);
    *(uint4*)(eaP + (size_t)p*64 + q*8) = o;
}

// ---------------- node projection: h = x @ pW + pb -----------------------------
__global__ __launch_bounds__(256) void node_proj(const float* __restrict__ x,
                                                 const float* __restrict__ pb,
                                                 const u16* __restrict__ wpack,
                                                 float* __restrict__ h,
                                                 u16* __restrict__ h_bf) {
    __shared__ __align__(16) u16 sX[64*136];
    const int tid = threadIdx.x;
    const int n0 = blockIdx.x * 64;
    for (int i = tid; i < 64*32; i += 256) {
        int node = i >> 5, c = i & 31;
        float4 v = make_float4(0.f, 0.f, 0.f, 0.f);
        if (n0 + node < NN) v = *(const float4*)(x + (size_t)(n0+node)*128 + c*4);
        *(uint2*)&sX[node*136 + c*4] = make_uint2(pk2(v.x, v.y), pk2(v.z, v.w));
    }
    __syncthreads();
    const int w = tid >> 6, L = tid & 63;
    const int m = L & 15, kc = L >> 4;
    const int wb = w * 16;
    const f32x4 z = {0.f, 0.f, 0.f, 0.f};
    f32x4 acc[4] = {z, z, z, z};
#pragma unroll
    for (int s = 0; s < 4; ++s) {
        s8v a = *(const s8v*)&sX[(wb+m)*136 + s*32 + kc*8];
#pragma unroll
        for (int t = 0; t < 4; ++t) {
            s8v bf = *(const s8v*)(wpack + ((size_t)(s*4+t)*64 + L)*8);
            acc[t] = __builtin_amdgcn_mfma_f32_16x16x32_bf16(a, bf, acc[t], 0, 0, 0);
        }
    }
#pragma unroll
    for (int t = 0; t < 4; ++t) {
        int u = t*16 + m;
        float bias = pb[u];
#pragma unroll
        for (int r = 0; r < 4; ++r) {
            int node = n0 + wb + kc*4 + r;
            if (node < NN) {
                float v = acc[t][r] + bias;
                h[(size_t)node*64 + u] = v;
                h_bf[(size_t)node*64 + u] = f2bf(v);
            }
        }
    }
}

// ---------------- fused per-layer edge kernel (sorted edges) -------------------
// 4 independent waves x 32 edges; NO block barriers. Per-wave LDS tile [32][STR]
// single-buffered. Latency discipline (R3 post-mortem: chain-bound, not
// resource-bound):
//  - ALL biases + segment mask computed up front (hidden under gathers)
//  - h_row fragments gathered ONCE, held in regs, reused by GEMM3
//  - parallel 4-accumulator segmented reduce (independent shfl chains)
// __launch_bounds__(256,4): 128-reg budget; ~100 live regs -> MUST NOT spill
// (R1's (256,6)=80-reg budget spilled acc -> +600 MB scratch traffic).
__global__ __launch_bounds__(256, 4) void edge_layer(const int2* __restrict__ rcP,
                                                     const u16* __restrict__ h_bf,
                                                     u16* __restrict__ ea_bf,
                                                     const u16* __restrict__ wp,
                                                     const float* __restrict__ eb1,
                                                     const float* __restrict__ eb2,
                                                     const float* __restrict__ nb1,
                                                     const float* __restrict__ nb2,
                                                     float* __restrict__ agg,
                                                     int save_ea) {
    __shared__ __align__(16) u16 sB[4*32*STR];   // 18,432 B
    const int tid = threadIdx.x;
    const int w = tid >> 6, L = tid & 63;
    const int m = L & 15, kc = L >> 4;
    const int wb = w * 32;
    const size_t e0 = (size_t)blockIdx.x * 128;
    u16* sW = sB + w * 32 * STR;

    // one coalesced 8B load covers this wave's 32 (row,col) pairs
    int2 rc0 = rcP[e0 + wb + (L & 31)];
    int lcol = rc0.y;

    // ---- prologue: everything the epilogues/reduce need, issued up front ----
    float be1[4], be2[4], bn1[4];
#pragma unroll
    for (int t = 0; t < 4; ++t) {
        int u = t*16 + m;
        be1[t] = eb1[u]; be2[t] = eb2[u]; bn1[t] = nb1[u];
    }
    float bn2L = nb2[L];

    unsigned long long smask;
    {
        int prev = __shfl(lcol, (L + 63) & 63);
        bool sstart = (L < 32) && ((L == 0) || (lcol != prev));
        smask = __ballot(sstart);
    }

    // gathered A-fragments: one epoch; h_row kept in regs for GEMM3 reuse
    s8v hrow[2][2], hcol[2][2];
#pragma unroll
    for (int g = 0; g < 2; ++g) {
        int rI = __shfl(rc0.x, g*16 + m);
        int cI = __shfl(rc0.y, g*16 + m);
        hrow[g][0] = *(const s8v*)(h_bf + (size_t)rI*64 + kc*8);
        hrow[g][1] = *(const s8v*)(h_bf + (size_t)rI*64 + 32 + kc*8);
        hcol[g][0] = *(const s8v*)(h_bf + (size_t)cI*64 + kc*8);
        hcol[g][1] = *(const s8v*)(h_bf + (size_t)cI*64 + 32 + kc*8);
    }

    const f32x4 z = {0.f, 0.f, 0.f, 0.f};
    f32x4 acc[2][4];

    // ---- GEMM1: [h_row|h_col|ea][*,192] @ eW1 -> t1 (LDS) ----
#pragma unroll
    for (int g = 0; g < 2; ++g)
#pragma unroll
        for (int t = 0; t < 4; ++t) acc[g][t] = z;
#pragma unroll
    for (int s = 0; s < 6; ++s) {
        s8v a[2];
#pragma unroll
        for (int g = 0; g < 2; ++g) {
            if (s < 2)
                a[g] = hrow[g][s];
            else if (s < 4)
                a[g] = hcol[g][s-2];
            else
                a[g] = *(const s8v*)(ea_bf + (e0 + wb + g*16 + m)*64 + (s-4)*32 + kc*8);
        }
#pragma unroll
        for (int t = 0; t < 4; ++t) {
            s8v bf = *(const s8v*)(wp + ((size_t)(s*4+t)*64 + L)*8);
            acc[0][t] = __builtin_amdgcn_mfma_f32_16x16x32_bf16(a[0], bf, acc[0][t], 0, 0, 0);
            acc[1][t] = __builtin_amdgcn_mfma_f32_16x16x32_bf16(a[1], bf, acc[1][t], 0, 0, 0);
        }
    }
#pragma unroll
    for (int g = 0; g < 2; ++g)
#pragma unroll
        for (int t = 0; t < 4; ++t) {
            int u = t*16 + m;
#pragma unroll
            for (int r = 0; r < 4; ++r) {
                float v = acc[g][t][r] + be1[t];
                v = v > 0.f ? v : 0.f;
                sW[(g*16 + kc*4 + r)*STR + u] = f2bf(v);
            }
        }

    // ---- GEMM2: t1 @ eW2 -> ea_new (overwrites t1 region after reads) ----
    const u16* wp2 = wp + 24*512;
#pragma unroll
    for (int g = 0; g < 2; ++g)
#pragma unroll
        for (int t = 0; t < 4; ++t) acc[g][t] = z;
#pragma unroll
    for (int s = 0; s < 2; ++s) {
        s8v a0 = *(const s8v*)&sW[(m)*STR + s*32 + kc*8];
        s8v a1 = *(const s8v*)&sW[(16 + m)*STR + s*32 + kc*8];
#pragma unroll
        for (int t = 0; t < 4; ++t) {
            s8v bf = *(const s8v*)(wp2 + ((size_t)(s*4+t)*64 + L)*8);
            acc[0][t] = __builtin_amdgcn_mfma_f32_16x16x32_bf16(a0, bf, acc[0][t], 0, 0, 0);
            acc[1][t] = __builtin_amdgcn_mfma_f32_16x16x32_bf16(a1, bf, acc[1][t], 0, 0, 0);
        }
    }
#pragma unroll
    for (int g = 0; g < 2; ++g)
#pragma unroll
        for (int t = 0; t < 4; ++t) {
            int u = t*16 + m;
#pragma unroll
            for (int r = 0; r < 4; ++r) {
                float v = acc[g][t][r] + be2[t];
                sW[(g*16 + kc*4 + r)*STR + u] = f2bf(v);
            }
        }

    // ---- GEMM3: [h_row|ea_new][*,128] @ nW1 -> t2; optionally persist ea_new ----
    // h_row operands reused from registers (no re-gather).
    const u16* wp3 = wp + 32*512;
#pragma unroll
    for (int g = 0; g < 2; ++g)
#pragma unroll
        for (int t = 0; t < 4; ++t) acc[g][t] = z;
#pragma unroll
    for (int s = 0; s < 4; ++s) {
        s8v a[2];
#pragma unroll
        for (int g = 0; g < 2; ++g) {
            if (s < 2) {
                a[g] = hrow[g][s];
            } else {
                a[g] = *(const s8v*)&sW[(g*16 + m)*STR + (s-2)*32 + kc*8];
                if (save_ea)
                    *(s8v*)(ea_bf + (e0 + wb + g*16 + m)*64 + (s-2)*32 + kc*8) = a[g];
            }
        }
#pragma unroll
        for (int t = 0; t < 4; ++t) {
            s8v bf = *(const s8v*)(wp3 + ((size_t)(s*4+t)*64 + L)*8);
            acc[0][t] = __builtin_amdgcn_mfma_f32_16x16x32_bf16(a[0], bf, acc[0][t], 0, 0, 0);
            acc[1][t] = __builtin_amdgcn_mfma_f32_16x16x32_bf16(a[1], bf, acc[1][t], 0, 0, 0);
        }
    }
#pragma unroll
    for (int g = 0; g < 2; ++g)
#pragma unroll
        for (int t = 0; t < 4; ++t) {
            int u = t*16 + m;
#pragma unroll
            for (int r = 0; r < 4; ++r) {
                float v = acc[g][t][r] + bn1[t];
                v = v > 0.f ? v : 0.f;
                sW[(g*16 + kc*4 + r)*STR + u] = f2bf(v);
            }
        }

    // ---- GEMM4: t2 @ nW2 -> msg (stays in acc registers) ----
    const u16* wp4 = wp + 48*512;
#pragma unroll
    for (int g = 0; g < 2; ++g)
#pragma unroll
        for (int t = 0; t < 4; ++t) acc[g][t] = z;
#pragma unroll
    for (int s = 0; s < 2; ++s) {
        s8v a0 = *(const s8v*)&sW[(m)*STR + s*32 + kc*8];
        s8v a1 = *(const s8v*)&sW[(16 + m)*STR + s*32 + kc*8];
#pragma unroll
        for (int t = 0; t < 4; ++t) {
            s8v bf = *(const s8v*)(wp4 + ((size_t)(s*4+t)*64 + L)*8);
            acc[0][t] = __builtin_amdgcn_mfma_f32_16x16x32_bf16(a0, bf, acc[0][t], 0, 0, 0);
            acc[1][t] = __builtin_amdgcn_mfma_f32_16x16x32_bf16(a1, bf, acc[1][t], 0, 0, 0);
        }
    }

    // ---- per-wave in-register segmented reduction -----------------------------
    // acc[g][t][r]: edge le = g*16 + kc*4 + r, feature f = t*16 + m. Lane L's
    // target feature is L = kc*16 + m (pick t == kc after cross-kc reduce).
    // 4 independent partials -> shfl chains overlap (R3's sequential-t version
    // serialized 8 dependent shfl pairs per segment).
    while (smask) {
        int beg = (int)__builtin_ctzll(smask);
        smask &= smask - 1;
        int end = smask ? (int)__builtin_ctzll(smask) : 32;
        int node = __shfl(lcol, beg);
        float r0 = 0.f, r1 = 0.f, r2 = 0.f, r3 = 0.f;
#pragma unroll
        for (int g = 0; g < 2; ++g)
#pragma unroll
            for (int r = 0; r < 4; ++r) {
                int le = g*16 + kc*4 + r;
                bool in = (le >= beg) && (le < end);
                r0 += in ? acc[g][0][r] : 0.f;
                r1 += in ? acc[g][1][r] : 0.f;
                r2 += in ? acc[g][2][r] : 0.f;
                r3 += in ? acc[g][3][r] : 0.f;
            }
        r0 += __shfl_xor(r0, 16); r0 += __shfl_xor(r0, 32);
        r1 += __shfl_xor(r1, 16); r1 += __shfl_xor(r1, 32);
        r2 += __shfl_xor(r2, 16); r2 += __shfl_xor(r2, 32);
        r3 += __shfl_xor(r3, 16); r3 += __shfl_xor(r3, 32);
        float rv = (kc == 0) ? r0 : (kc == 1) ? r1 : (kc == 2) ? r2 : r3;
        rv += (float)(end - beg) * bn2L;
        unsafeAtomicAdd(&agg[(size_t)node*64 + L], rv);
    }
}

// ---------------- h = relu(agg + h); refresh bf16 copy; re-zero agg ------------
__global__ void update_h(float* __restrict__ h, float* __restrict__ agg,
                         u16* __restrict__ h_bf, int zero_agg, int write_hbf) {
    int i = (blockIdx.x * 256 + threadIdx.x) * 4;
    float4 a = *(const float4*)(agg + i);
    float4 hv = *(const float4*)(h + i);
    float4 v;
    v.x = fmaxf(a.x + hv.x, 0.f);
    v.y = fmaxf(a.y + hv.y, 0.f);
    v.z = fmaxf(a.z + hv.z, 0.f);
    v.w = fmaxf(a.w + hv.w, 0.f);
    *(float4*)(h + i) = v;
    if (write_hbf) *(uint2*)(h_bf + i) = make_uint2(pk2(v.x, v.y), pk2(v.z, v.w));
    if (zero_agg) *(float4*)(agg + i) = make_float4(0.f, 0.f, 0.f, 0.f);
}

// ---------------- mean pool ----------------------------------------------------
__global__ void pool1(const float* __restrict__ h, float* __restrict__ pooled) {
    float acc = 0.f;
    const int stride = gridDim.x * 256;
    for (int i = blockIdx.x * 256 + threadIdx.x; i < NN*64; i += stride)
        acc += h[i];
    __shared__ float sp[256];
    sp[threadIdx.x] = acc;
    __syncthreads();
    if (threadIdx.x < 64) {
        float v = sp[threadIdx.x] + sp[threadIdx.x+64] + sp[threadIdx.x+128] + sp[threadIdx.x+192];
        unsafeAtomicAdd(&pooled[threadIdx.x], v);
    }
}

__global__ void pool2(const float* __restrict__ pooled, const float* __restrict__ lW,
                      const float* __restrict__ lb, float* __restrict__ out) {
    int k = threadIdx.x;   // 64 threads
    float v = pooled[k] * (1.0f / NN);
#pragma unroll
    for (int o = 0; o < 3; ++o) {
        float p = v * lW[k*3 + o];
        for (int off = 32; off > 0; off >>= 1)
            p += __shfl_down(p, off);
        if (k == 0) out[o] = p + lb[o];
    }
}

extern "C" void kernel_launch(void* const* d_in, const int* in_sizes, int n_in,
                              void* d_out, int out_size, void* d_ws, size_t ws_size,
                              hipStream_t stream) {
    const float* x         = (const float*)d_in[0];
    const int*   ei        = (const int*)d_in[1];
    const float* edge_attr = (const float*)d_in[2];
    const float* pW        = (const float*)d_in[3];
    const float* pb        = (const float*)d_in[4];
    const float* eW1       = (const float*)d_in[5];
    const float* eb1       = (const float*)d_in[6];
    const float* eW2       = (const float*)d_in[7];
    const float* eb2       = (const float*)d_in[8];
    const float* nW1       = (const float*)d_in[9];
    const float* nb1       = (const float*)d_in[10];
    const float* nW2       = (const float*)d_in[11];
    const float* nb2       = (const float*)d_in[12];
    const float* lW        = (const float*)d_in[13];
    const float* lb        = (const float*)d_in[14];
    float* out = (float*)d_out;

    char* ws = (char*)d_ws;
    float* h     = (float*)(ws);                         // 25,600,000 B
    float* agg   = (float*)(ws + 25600000);              // 25,600,000 B
    u16*   h_bf  = (u16*)  (ws + 51200000);              // 12,800,000 B
    u16*   eaP   = (u16*)  (ws + 64000000);              // 204,800,000 B (sorted-order ea)
    u16*   wpack = (u16*)  (ws + 268800000);             // 188,416 B
    float* pooled= (float*)(ws + 268988416);             // 256 B
    int2*  rcP   = (int2*) (ws + 268988672);             // 12,800,000 B (ends 281,788,672)
    // sort scratch overlaid on agg (dead until after preprocessing):
    int* hist      = (int*)agg;                          // BINS_PAD ints
    int* cursor    = hist + BINS_PAD;                    // BINS_PAD ints
    int* blockSums = cursor + BINS_PAD;                  // 128 ints
    int* pos       = blockSums + 128;                    // NE ints (~7.2 MB total < 25.6 MB)

    // ---- counting sort by col (once; reused by all 3 layers) ----
    hipMemsetAsync(hist, 0, BINS_PAD*4, stream);
    k_hist<<<NE/256, 256, 0, stream>>>(ei, hist);
    k_scan1<<<98, 256, 0, stream>>>(hist, cursor, blockSums);
    k_scan2<<<1, 128, 0, stream>>>(blockSums);
    k_scan3<<<98, 256, 0, stream>>>(cursor, blockSums);
    k_scatter<<<NE/256, 256, 0, stream>>>(ei, cursor, rcP, pos);
    k_permute_ea<<<NE*8/256, 256, 0, stream>>>(edge_attr, pos, eaP);

    pack_weights<<<184, 64, 0, stream>>>(pW, eW1, eW2, nW1, nW2, wpack);
    node_proj<<<(NN + 63)/64, 256, 0, stream>>>(x, pb, wpack, h, h_bf);

    hipMemsetAsync(agg, 0, (size_t)NN*64*4, stream);     // clobbers sort scratch (dead)
    for (int l = 0; l < 3; ++l) {
        edge_layer<<<NE/128, 256, 0, stream>>>(rcP, h_bf, eaP,
                                               wpack + (16 + l*56)*512,
                                               eb1 + l*64, eb2 + l*64, nb1 + l*64, nb2 + l*64,
                                               agg, l < 2 ? 1 : 0);
        update_h<<<NN*64/4/256, 256, 0, stream>>>(h, agg, h_bf, l < 2 ? 1 : 0, l < 2 ? 1 : 0);
    }
    hipMemsetAsync(pooled, 0, 64*4, stream);
    pool1<<<256, 256, 0, stream>>>(h, pooled);
    pool2<<<1, 64, 0, stream>>>(pooled, lW, lb, out);
}

// Round 8
// 1488.541 us; speedup vs baseline: 1.3062x; 1.0782x over previous
//
#include <hip/hip_runtime.h>

#define NN 100000
#define NE 1600000
#define BINS_PAD 100352   // 98 * 1024 >= NN
#define STR 72            // per-wave LDS row stride (u16), 16B-aligned rows

typedef short s8v __attribute__((ext_vector_type(8)));
typedef float f32x4 __attribute__((ext_vector_type(4)));
typedef unsigned short u16;

__device__ __forceinline__ u16 f2bf(float f) {
    union { float f; unsigned u; } v; v.f = f;
    unsigned r = v.u + 0x7FFFu + ((v.u >> 16) & 1u);
    return (u16)(r >> 16);
}
__device__ __forceinline__ unsigned pk2(float a, float b) {
    return (unsigned)f2bf(a) | ((unsigned)f2bf(b) << 16);
}
// HW packed f32->bf16 (RTNE), 1 instr per 2 values (no builtin on gfx950)
__device__ __forceinline__ unsigned cvtpk(float a, float b) {
    unsigned r;
    asm("v_cvt_pk_bf16_f32 %0, %1, %2" : "=v"(r) : "v"(a), "v"(b));
    return r;
}
__device__ __forceinline__ s8v pack8(float4 a, float4 b) {
    union { s8v v; unsigned u[4]; } o;
    o.u[0] = cvtpk(a.x, a.y); o.u[1] = cvtpk(a.z, a.w);
    o.u[2] = cvtpk(b.x, b.y); o.u[3] = cvtpk(b.z, b.w);
    return o.v;
}

// ---------------- weight fragment packing (bf16, B-operand layout) -------------
__global__ void pack_weights(const float* __restrict__ pW,
                             const float* __restrict__ eW1, const float* __restrict__ eW2,
                             const float* __restrict__ nW1, const float* __restrict__ nW2,
                             u16* __restrict__ wpack) {
    int b = blockIdx.x, L = threadIdx.x;
    const float* src; int s, t;
    if (b < 16) { src = pW; s = b >> 2; t = b & 3; }
    else {
        int bb = b - 16, l = bb / 56, r = bb % 56;
        if (r < 24)      {            src = eW1 + l*192*64; s = r>>2; t = r&3; }
        else if (r < 32) { r -= 24;   src = eW2 + l*64*64;  s = r>>2; t = r&3; }
        else if (r < 48) { r -= 32;   src = nW1 + l*128*64; s = r>>2; t = r&3; }
        else             { r -= 48;   src = nW2 + l*64*64;  s = r>>2; t = r&3; }
    }
    int kbase = s*32 + (L>>4)*8;
    int n = t*16 + (L&15);
    u16* dst = wpack + (size_t)b*512 + (size_t)L*8;
#pragma unroll
    for (int j = 0; j < 8; ++j) dst[j] = f2bf(src[(kbase+j)*64 + n]);
}

// ---------------- counting sort of edges by col --------------------------------
__global__ void k_hist(const int* __restrict__ ei, int* __restrict__ hist) {
    int e = blockIdx.x * 256 + threadIdx.x;
    atomicAdd(&hist[ei[(size_t)NE + e]], 1);
}

__global__ void k_scan1(const int* __restrict__ hist, int* __restrict__ cursor,
                        int* __restrict__ blockSums) {
    __shared__ int sS[256];
    int t = threadIdx.x, b = blockIdx.x;
    int base = b*1024 + t*4;
    int v0 = hist[base], v1 = hist[base+1], v2 = hist[base+2], v3 = hist[base+3];
    int s4 = v0 + v1 + v2 + v3;
    sS[t] = s4; __syncthreads();
    for (int off = 1; off < 256; off <<= 1) {
        int x = (t >= off) ? sS[t-off] : 0;
        __syncthreads();
        sS[t] += x;
        __syncthreads();
    }
    int excl = sS[t] - s4;
    cursor[base] = excl; cursor[base+1] = excl+v0;
    cursor[base+2] = excl+v0+v1; cursor[base+3] = excl+v0+v1+v2;
    if (t == 255) blockSums[b] = sS[255];
}

__global__ void k_scan2(int* __restrict__ blockSums) {
    __shared__ int sS[128];
    int t = threadIdx.x;
    int v = (t < 98) ? blockSums[t] : 0;
    sS[t] = v; __syncthreads();
    for (int off = 1; off < 128; off <<= 1) {
        int x = (t >= off) ? sS[t-off] : 0;
        __syncthreads();
        sS[t] += x;
        __syncthreads();
    }
    if (t < 98) blockSums[t] = sS[t] - v;   // exclusive
}

__global__ void k_scan3(int* __restrict__ cursor, const int* __restrict__ blockSums) {
    int i = blockIdx.x*1024 + threadIdx.x*4;
    int add = blockSums[blockIdx.x];
    cursor[i] += add; cursor[i+1] += add; cursor[i+2] += add; cursor[i+3] += add;
}

// scatter: rcP[p]={row,col}; inv[p]=orig edge (for layer-0 direct ea gather)
__global__ void k_scatter(const int* __restrict__ ei, int* __restrict__ cursor,
                          int2* __restrict__ rcP, int* __restrict__ inv) {
    int e = blockIdx.x * 256 + threadIdx.x;
    int c = ei[(size_t)NE + e];
    int p = atomicAdd(&cursor[c], 1);
    rcP[p] = make_int2(ei[e], c);
    inv[p] = e;
}

// ---------------- node projection: h = x @ pW + pb -----------------------------
__global__ __launch_bounds__(256) void node_proj(const float* __restrict__ x,
                                                 const float* __restrict__ pb,
                                                 const u16* __restrict__ wpack,
                                                 float* __restrict__ h,
                                                 u16* __restrict__ h_bf) {
    __shared__ __align__(16) u16 sX[64*136];
    const int tid = threadIdx.x;
    const int n0 = blockIdx.x * 64;
    for (int i = tid; i < 64*32; i += 256) {
        int node = i >> 5, c = i & 31;
        float4 v = make_float4(0.f, 0.f, 0.f, 0.f);
        if (n0 + node < NN) v = *(const float4*)(x + (size_t)(n0+node)*128 + c*4);
        *(uint2*)&sX[node*136 + c*4] = make_uint2(pk2(v.x, v.y), pk2(v.z, v.w));
    }
    __syncthreads();
    const int w = tid >> 6, L = tid & 63;
    const int m = L & 15, kc = L >> 4;
    const int wb = w * 16;
    const f32x4 z = {0.f, 0.f, 0.f, 0.f};
    f32x4 acc[4] = {z, z, z, z};
#pragma unroll
    for (int s = 0; s < 4; ++s) {
        s8v a = *(const s8v*)&sX[(wb+m)*136 + s*32 + kc*8];
#pragma unroll
        for (int t = 0; t < 4; ++t) {
            s8v bf = *(const s8v*)(wpack + ((size_t)(s*4+t)*64 + L)*8);
            acc[t] = __builtin_amdgcn_mfma_f32_16x16x32_bf16(a, bf, acc[t], 0, 0, 0);
        }
    }
#pragma unroll
    for (int t = 0; t < 4; ++t) {
        int u = t*16 + m;
        float bias = pb[u];
#pragma unroll
        for (int r = 0; r < 4; ++r) {
            int node = n0 + wb + kc*4 + r;
            if (node < NN) {
                float v = acc[t][r] + bias;
                h[(size_t)node*64 + u] = v;
                h_bf[(size_t)node*64 + u] = f2bf(v);
            }
        }
    }
}

// ---------------- fused per-layer edge kernel (sorted edges) -------------------
// 4 independent waves x 32 edges; NO block barriers. Per-wave LDS tile [32][STR]
// single-buffered. FIRST=1: gather ORIGINAL f32 edge_attr via inv[] + HW
// cvt_pk (kills the standalone permute kernel); FIRST=0: read sorted bf16 eaP.
// All A-operands (hrow/hcol/ea) staged to regs in ONE prologue epoch; h_row
// reused by GEMM3. Epilogues use v_cvt_pk_bf16_f32 (1 instr / 2 values vs 4).
// __launch_bounds__(256,4): 128-reg budget; MUST NOT spill (R1 lesson).
template<int FIRST>
__global__ __launch_bounds__(256, 4) void edge_layer(const int2* __restrict__ rcP,
                                                     const int* __restrict__ inv,
                                                     const u16* __restrict__ h_bf,
                                                     const float* __restrict__ ea0,
                                                     u16* __restrict__ ea_bf,
                                                     const u16* __restrict__ wp,
                                                     const float* __restrict__ eb1,
                                                     const float* __restrict__ eb2,
                                                     const float* __restrict__ nb1,
                                                     const float* __restrict__ nb2,
                                                     float* __restrict__ agg,
                                                     int save_ea) {
    __shared__ __align__(16) u16 sB[4*32*STR];   // 18,432 B
    const int tid = threadIdx.x;
    const int w = tid >> 6, L = tid & 63;
    const int m = L & 15, kc = L >> 4;
    const int wb = w * 32;
    const size_t e0 = (size_t)blockIdx.x * 128;
    u16* sW = sB + w * 32 * STR;

    // one coalesced 8B load covers this wave's 32 (row,col) pairs
    int2 rc0 = rcP[e0 + wb + (L & 31)];
    int lcol = rc0.y;
    int ie = 0;
    if (FIRST) ie = inv[e0 + wb + (L & 31)];

    // ---- prologue: biases, segment mask, ALL gathered A-fragments -------------
    float be1[4], be2[4], bn1[4];
#pragma unroll
    for (int t = 0; t < 4; ++t) {
        int u = t*16 + m;
        be1[t] = eb1[u]; be2[t] = eb2[u]; bn1[t] = nb1[u];
    }
    float bn2L = nb2[L];

    unsigned long long smask;
    {
        int prev = __shfl(lcol, (L + 63) & 63);
        bool sstart = (L < 32) && ((L == 0) || (lcol != prev));
        smask = __ballot(sstart);
    }

    s8v hrow[2][2], hcol[2][2], eafr[2][2];
#pragma unroll
    for (int g = 0; g < 2; ++g) {
        int rI = __shfl(rc0.x, g*16 + m);
        int cI = __shfl(rc0.y, g*16 + m);
        hrow[g][0] = *(const s8v*)(h_bf + (size_t)rI*64 + kc*8);
        hrow[g][1] = *(const s8v*)(h_bf + (size_t)rI*64 + 32 + kc*8);
        hcol[g][0] = *(const s8v*)(h_bf + (size_t)cI*64 + kc*8);
        hcol[g][1] = *(const s8v*)(h_bf + (size_t)cI*64 + 32 + kc*8);
    }
    if (FIRST) {
#pragma unroll
        for (int g = 0; g < 2; ++g) {
            int eIg = __shfl(ie, g*16 + m);
            const float* base = ea0 + (size_t)eIg*64 + kc*8;
#pragma unroll
            for (int s2 = 0; s2 < 2; ++s2) {
                float4 f0 = *(const float4*)(base + s2*32);
                float4 f1 = *(const float4*)(base + s2*32 + 4);
                eafr[g][s2] = pack8(f0, f1);
            }
        }
    } else {
#pragma unroll
        for (int g = 0; g < 2; ++g)
#pragma unroll
            for (int s2 = 0; s2 < 2; ++s2)
                eafr[g][s2] = *(const s8v*)(ea_bf + (e0 + wb + g*16 + m)*64 + s2*32 + kc*8);
    }

    const f32x4 z = {0.f, 0.f, 0.f, 0.f};
    f32x4 acc[2][4];

    // ---- GEMM1: [h_row|h_col|ea][*,192] @ eW1 -> t1 (LDS) ----
#pragma unroll
    for (int g = 0; g < 2; ++g)
#pragma unroll
        for (int t = 0; t < 4; ++t) acc[g][t] = z;
#pragma unroll
    for (int s = 0; s < 6; ++s) {
        s8v a[2];
#pragma unroll
        for (int g = 0; g < 2; ++g)
            a[g] = (s < 2) ? hrow[g][s] : (s < 4) ? hcol[g][s-2] : eafr[g][s-4];
#pragma unroll
        for (int t = 0; t < 4; ++t) {
            s8v bf = *(const s8v*)(wp + ((size_t)(s*4+t)*64 + L)*8);
            acc[0][t] = __builtin_amdgcn_mfma_f32_16x16x32_bf16(a[0], bf, acc[0][t], 0, 0, 0);
            acc[1][t] = __builtin_amdgcn_mfma_f32_16x16x32_bf16(a[1], bf, acc[1][t], 0, 0, 0);
        }
    }
#pragma unroll
    for (int g = 0; g < 2; ++g)
#pragma unroll
        for (int t = 0; t < 4; ++t) {
            int u = t*16 + m;
            float v0 = fmaxf(acc[g][t][0] + be1[t], 0.f);
            float v1 = fmaxf(acc[g][t][1] + be1[t], 0.f);
            float v2 = fmaxf(acc[g][t][2] + be1[t], 0.f);
            float v3 = fmaxf(acc[g][t][3] + be1[t], 0.f);
            unsigned w01 = cvtpk(v0, v1), w23 = cvtpk(v2, v3);
            int rb = (g*16 + kc*4)*STR + u;
            sW[rb]         = (u16)w01;
            sW[rb + STR]   = (u16)(w01 >> 16);
            sW[rb + 2*STR] = (u16)w23;
            sW[rb + 3*STR] = (u16)(w23 >> 16);
        }

    // ---- GEMM2: t1 @ eW2 -> ea_new (overwrites t1 region after reads) ----
    const u16* wp2 = wp + 24*512;
#pragma unroll
    for (int g = 0; g < 2; ++g)
#pragma unroll
        for (int t = 0; t < 4; ++t) acc[g][t] = z;
#pragma unroll
    for (int s = 0; s < 2; ++s) {
        s8v a0 = *(const s8v*)&sW[(m)*STR + s*32 + kc*8];
        s8v a1 = *(const s8v*)&sW[(16 + m)*STR + s*32 + kc*8];
#pragma unroll
        for (int t = 0; t < 4; ++t) {
            s8v bf = *(const s8v*)(wp2 + ((size_t)(s*4+t)*64 + L)*8);
            acc[0][t] = __builtin_amdgcn_mfma_f32_16x16x32_bf16(a0, bf, acc[0][t], 0, 0, 0);
            acc[1][t] = __builtin_amdgcn_mfma_f32_16x16x32_bf16(a1, bf, acc[1][t], 0, 0, 0);
        }
    }
#pragma unroll
    for (int g = 0; g < 2; ++g)
#pragma unroll
        for (int t = 0; t < 4; ++t) {
            int u = t*16 + m;
            float v0 = acc[g][t][0] + be2[t];
            float v1 = acc[g][t][1] + be2[t];
            float v2 = acc[g][t][2] + be2[t];
            float v3 = acc[g][t][3] + be2[t];
            unsigned w01 = cvtpk(v0, v1), w23 = cvtpk(v2, v3);
            int rb = (g*16 + kc*4)*STR + u;
            sW[rb]         = (u16)w01;
            sW[rb + STR]   = (u16)(w01 >> 16);
            sW[rb + 2*STR] = (u16)w23;
            sW[rb + 3*STR] = (u16)(w23 >> 16);
        }

    // ---- GEMM3: [h_row|ea_new][*,128] @ nW1 -> t2; optionally persist ea_new ----
    const u16* wp3 = wp + 32*512;
#pragma unroll
    for (int g = 0; g < 2; ++g)
#pragma unroll
        for (int t = 0; t < 4; ++t) acc[g][t] = z;
#pragma unroll
    for (int s = 0; s < 4; ++s) {
        s8v a[2];
#pragma unroll
        for (int g = 0; g < 2; ++g) {
            if (s < 2) {
                a[g] = hrow[g][s];
            } else {
                a[g] = *(const s8v*)&sW[(g*16 + m)*STR + (s-2)*32 + kc*8];
                if (save_ea)
                    *(s8v*)(ea_bf + (e0 + wb + g*16 + m)*64 + (s-2)*32 + kc*8) = a[g];
            }
        }
#pragma unroll
        for (int t = 0; t < 4; ++t) {
            s8v bf = *(const s8v*)(wp3 + ((size_t)(s*4+t)*64 + L)*8);
            acc[0][t] = __builtin_amdgcn_mfma_f32_16x16x32_bf16(a[0], bf, acc[0][t], 0, 0, 0);
            acc[1][t] = __builtin_amdgcn_mfma_f32_16x16x32_bf16(a[1], bf, acc[1][t], 0, 0, 0);
        }
    }
#pragma unroll
    for (int g = 0; g < 2; ++g)
#pragma unroll
        for (int t = 0; t < 4; ++t) {
            int u = t*16 + m;
            float v0 = fmaxf(acc[g][t][0] + bn1[t], 0.f);
            float v1 = fmaxf(acc[g][t][1] + bn1[t], 0.f);
            float v2 = fmaxf(acc[g][t][2] + bn1[t], 0.f);
            float v3 = fmaxf(acc[g][t][3] + bn1[t], 0.f);
            unsigned w01 = cvtpk(v0, v1), w23 = cvtpk(v2, v3);
            int rb = (g*16 + kc*4)*STR + u;
            sW[rb]         = (u16)w01;
            sW[rb + STR]   = (u16)(w01 >> 16);
            sW[rb + 2*STR] = (u16)w23;
            sW[rb + 3*STR] = (u16)(w23 >> 16);
        }

    // ---- GEMM4: t2 @ nW2 -> msg (stays in acc registers) ----
    const u16* wp4 = wp + 48*512;
#pragma unroll
    for (int g = 0; g < 2; ++g)
#pragma unroll
        for (int t = 0; t < 4; ++t) acc[g][t] = z;
#pragma unroll
    for (int s = 0; s < 2; ++s) {
        s8v a0 = *(const s8v*)&sW[(m)*STR + s*32 + kc*8];
        s8v a1 = *(const s8v*)&sW[(16 + m)*STR + s*32 + kc*8];
#pragma unroll
        for (int t = 0; t < 4; ++t) {
            s8v bf = *(const s8v*)(wp4 + ((size_t)(s*4+t)*64 + L)*8);
            acc[0][t] = __builtin_amdgcn_mfma_f32_16x16x32_bf16(a0, bf, acc[0][t], 0, 0, 0);
            acc[1][t] = __builtin_amdgcn_mfma_f32_16x16x32_bf16(a1, bf, acc[1][t], 0, 0, 0);
        }
    }

    // ---- per-wave in-register segmented reduction -----------------------------
    // acc[g][t][r]: edge le = g*16 + kc*4 + r, feature f = t*16 + m. Lane L's
    // target feature is L = kc*16 + m (pick t == kc after cross-kc reduce).
    while (smask) {
        int beg = (int)__builtin_ctzll(smask);
        smask &= smask - 1;
        int end = smask ? (int)__builtin_ctzll(smask) : 32;
        int node = __shfl(lcol, beg);
        float r0 = 0.f, r1 = 0.f, r2 = 0.f, r3 = 0.f;
#pragma unroll
        for (int g = 0; g < 2; ++g)
#pragma unroll
            for (int r = 0; r < 4; ++r) {
                int le = g*16 + kc*4 + r;
                bool in = (le >= beg) && (le < end);
                r0 += in ? acc[g][0][r] : 0.f;
                r1 += in ? acc[g][1][r] : 0.f;
                r2 += in ? acc[g][2][r] : 0.f;
                r3 += in ? acc[g][3][r] : 0.f;
            }
        r0 += __shfl_xor(r0, 16); r0 += __shfl_xor(r0, 32);
        r1 += __shfl_xor(r1, 16); r1 += __shfl_xor(r1, 32);
        r2 += __shfl_xor(r2, 16); r2 += __shfl_xor(r2, 32);
        r3 += __shfl_xor(r3, 16); r3 += __shfl_xor(r3, 32);
        float rv = (kc == 0) ? r0 : (kc == 1) ? r1 : (kc == 2) ? r2 : r3;
        rv += (float)(end - beg) * bn2L;
        unsafeAtomicAdd(&agg[(size_t)node*64 + L], rv);
    }
}

// ---------------- h = relu(agg + h); refresh bf16 copy; re-zero agg ------------
__global__ void update_h(float* __restrict__ h, float* __restrict__ agg,
                         u16* __restrict__ h_bf, int zero_agg, int write_hbf) {
    int i = (blockIdx.x * 256 + threadIdx.x) * 4;
    float4 a = *(const float4*)(agg + i);
    float4 hv = *(const float4*)(h + i);
    float4 v;
    v.x = fmaxf(a.x + hv.x, 0.f);
    v.y = fmaxf(a.y + hv.y, 0.f);
    v.z = fmaxf(a.z + hv.z, 0.f);
    v.w = fmaxf(a.w + hv.w, 0.f);
    *(float4*)(h + i) = v;
    if (write_hbf) *(uint2*)(h_bf + i) = make_uint2(pk2(v.x, v.y), pk2(v.z, v.w));
    if (zero_agg) *(float4*)(agg + i) = make_float4(0.f, 0.f, 0.f, 0.f);
}

// ---------------- mean pool ----------------------------------------------------
__global__ void pool1(const float* __restrict__ h, float* __restrict__ pooled) {
    float acc = 0.f;
    const int stride = gridDim.x * 256;
    for (int i = blockIdx.x * 256 + threadIdx.x; i < NN*64; i += stride)
        acc += h[i];
    __shared__ float sp[256];
    sp[threadIdx.x] = acc;
    __syncthreads();
    if (threadIdx.x < 64) {
        float v = sp[threadIdx.x] + sp[threadIdx.x+64] + sp[threadIdx.x+128] + sp[threadIdx.x+192];
        unsafeAtomicAdd(&pooled[threadIdx.x], v);
    }
}

__global__ void pool2(const float* __restrict__ pooled, const float* __restrict__ lW,
                      const float* __restrict__ lb, float* __restrict__ out) {
    int k = threadIdx.x;   // 64 threads
    float v = pooled[k] * (1.0f / NN);
#pragma unroll
    for (int o = 0; o < 3; ++o) {
        float p = v * lW[k*3 + o];
        for (int off = 32; off > 0; off >>= 1)
            p += __shfl_down(p, off);
        if (k == 0) out[o] = p + lb[o];
    }
}

extern "C" void kernel_launch(void* const* d_in, const int* in_sizes, int n_in,
                              void* d_out, int out_size, void* d_ws, size_t ws_size,
                              hipStream_t stream) {
    const float* x         = (const float*)d_in[0];
    const int*   ei        = (const int*)d_in[1];
    const float* edge_attr = (const float*)d_in[2];
    const float* pW        = (const float*)d_in[3];
    const float* pb        = (const float*)d_in[4];
    const float* eW1       = (const float*)d_in[5];
    const float* eb1       = (const float*)d_in[6];
    const float* eW2       = (const float*)d_in[7];
    const float* eb2       = (const float*)d_in[8];
    const float* nW1       = (const float*)d_in[9];
    const float* nb1       = (const float*)d_in[10];
    const float* nW2       = (const float*)d_in[11];
    const float* nb2       = (const float*)d_in[12];
    const float* lW        = (const float*)d_in[13];
    const float* lb        = (const float*)d_in[14];
    float* out = (float*)d_out;

    char* ws = (char*)d_ws;
    float* h     = (float*)(ws);                         // 25,600,000 B
    float* agg   = (float*)(ws + 25600000);              // 25,600,000 B
    u16*   h_bf  = (u16*)  (ws + 51200000);              // 12,800,000 B
    u16*   eaP   = (u16*)  (ws + 64000000);              // 204,800,000 B (sorted ea, layers 0/1 -> 1/2)
    u16*   wpack = (u16*)  (ws + 268800000);             // 188,416 B
    float* pooled= (float*)(ws + 268988416);             // 256 B
    int2*  rcP   = (int2*) (ws + 268988672);             // 12,800,000 B
    int*   inv   = (int*)  (ws + 281788672);             // 6,400,000 B (ends 288,188,672)
    // sort scratch overlaid on agg (dead until after preprocessing):
    int* hist      = (int*)agg;                          // BINS_PAD ints
    int* cursor    = hist + BINS_PAD;                    // BINS_PAD ints
    int* blockSums = cursor + BINS_PAD;                  // 128 ints

    // ---- counting sort by col (once; reused by all 3 layers) ----
    hipMemsetAsync(hist, 0, BINS_PAD*4, stream);
    k_hist<<<NE/256, 256, 0, stream>>>(ei, hist);
    k_scan1<<<98, 256, 0, stream>>>(hist, cursor, blockSums);
    k_scan2<<<1, 128, 0, stream>>>(blockSums);
    k_scan3<<<98, 256, 0, stream>>>(cursor, blockSums);
    k_scatter<<<NE/256, 256, 0, stream>>>(ei, cursor, rcP, inv);

    pack_weights<<<184, 64, 0, stream>>>(pW, eW1, eW2, nW1, nW2, wpack);
    node_proj<<<(NN + 63)/64, 256, 0, stream>>>(x, pb, wpack, h, h_bf);

    hipMemsetAsync(agg, 0, (size_t)NN*64*4, stream);     // clobbers sort scratch (dead)

    edge_layer<1><<<NE/128, 256, 0, stream>>>(rcP, inv, h_bf, edge_attr, eaP,
                                              wpack + 16*512,
                                              eb1, eb2, nb1, nb2, agg, 1);
    update_h<<<NN*64/4/256, 256, 0, stream>>>(h, agg, h_bf, 1, 1);

    edge_layer<0><<<NE/128, 256, 0, stream>>>(rcP, inv, h_bf, edge_attr, eaP,
                                              wpack + (16 + 56)*512,
                                              eb1 + 64, eb2 + 64, nb1 + 64, nb2 + 64, agg, 1);
    update_h<<<NN*64/4/256, 256, 0, stream>>>(h, agg, h_bf, 1, 1);

    edge_layer<0><<<NE/128, 256, 0, stream>>>(rcP, inv, h_bf, edge_attr, eaP,
                                              wpack + (16 + 112)*512,
                                              eb1 + 128, eb2 + 128, nb1 + 128, nb2 + 128, agg, 0);
    update_h<<<NN*64/4/256, 256, 0, stream>>>(h, agg, h_bf, 0, 0);

    hipMemsetAsync(pooled, 0, 64*4, stream);
    pool1<<<256, 256, 0, stream>>>(h, pooled);
    pool2<<<1, 64, 0, stream>>>(pooled, lW, lb, out);
}